// Round 17
// baseline (3667.954 us; speedup 1.0000x reference)
//
#include <hip/hip_runtime.h>
#include <hip/hip_bf16.h>
#include <cstdint>
#include <cstddef>

#define V_ 8192
#define D_ 1024
#define B_ 32
#define T_ 128
#define NBLK 16
#define SENT 0x7FC0u   // bf16 NaN — impossible tanh output

typedef __attribute__((ext_vector_type(8))) short bf16x8;
typedef __attribute__((ext_vector_type(4))) float f32x4;

__device__ __forceinline__ short f2bf(float f) {
  union { float f; unsigned u; } v; v.f = f;
  unsigned r = v.u + 0x7fffu + ((v.u >> 16) & 1u);
  return (short)(r >> 16);
}

__device__ __forceinline__ float bf2f(unsigned short u) {
  union { unsigned u; float f; } c; c.u = ((unsigned)u) << 16;
  return c.f;
}

// tanh(x) = 1 - 2/(exp2(2x*log2e)+1); exact at +/-inf, ~1e-7 abs err
__device__ __forceinline__ float fast_tanh(float x) {
  float t = __builtin_amdgcn_exp2f(x * 2.8853900817779268f);
  return 1.0f - 2.0f * __builtin_amdgcn_rcpf(t + 1.0f);
}

// async global->LDS, 16B per lane. lds base must be wave-uniform.
__device__ __forceinline__ void lds_load16(const void* g, void* l) {
  __builtin_amdgcn_global_load_lds(
      (const __attribute__((address_space(1))) unsigned int*)g,
      (__attribute__((address_space(3))) unsigned int*)l,
      16, 0, 0);
}

union U4 { int4 i4; unsigned u[4]; unsigned long long q[2]; bf16x8 v; };

// 4x dwordx4 sc0 loads (bypass L1 on miss path; served by this XCD's shared L2)
__device__ __forceinline__ void load_frag_sc0(const short* ap, U4* out) {
  asm volatile(
      "global_load_dwordx4 %0, %4, off sc0\n\t"
      "global_load_dwordx4 %1, %4, off offset:64 sc0\n\t"
      "global_load_dwordx4 %2, %4, off offset:128 sc0\n\t"
      "global_load_dwordx4 %3, %4, off offset:192 sc0\n\t"
      "s_waitcnt vmcnt(0)"
      : "=&v"(out[0].i4), "=&v"(out[1].i4), "=&v"(out[2].i4), "=&v"(out[3].i4)
      : "v"(ap) : "memory");
}

// ---------- f32 -> bf16 conversion ----------
__global__ __launch_bounds__(256) void conv_bf16_k(const float* __restrict__ in,
                                                   short* __restrict__ out, int n4) {
  int i = blockIdx.x * 256 + threadIdx.x;  // one float4 per thread
  if (i >= n4) return;
  float4 v = reinterpret_cast<const float4*>(in)[i];
  short4 o;
  o.x = f2bf(v.x); o.y = f2bf(v.y); o.z = f2bf(v.z); o.w = f2bf(v.w);
  reinterpret_cast<short4*>(out)[i] = o;
}

// ---------- W_hh split: Rb = bf16(W_hh, zero diag), Wdiag = diag(W_hh) f32 ----------
__global__ __launch_bounds__(256) void conv_whh(const float* __restrict__ W,
                                                short* __restrict__ Rb,
                                                float* __restrict__ Wdiag) {
  int i = blockIdx.x * 256 + threadIdx.x;   // over D*D = 1048576
  int n = i >> 10;
  int k = i & (D_ - 1);
  float w = W[i];
  Rb[i] = f2bf(k == n ? 0.0f : w);
  if (k == n) Wdiag[n] = w;
}

// ---------- fused: poison Af slots 1..128 + slot-0 init + flags + idxT ----------
__global__ __launch_bounds__(256) void prep_h(const float* __restrict__ h0,
                                              const int* __restrict__ idx,
                                              short* __restrict__ Af,
                                              unsigned* __restrict__ flags,
                                              int* __restrict__ idxT) {
  int i = blockIdx.x * 256 + threadIdx.x;   // 0..1048575 (u64 chunks of slots 1..128)
  __hip_atomic_store((unsigned long long*)(Af + B_ * D_) + i,
                     0x7FC07FC07FC07FC0ull, __ATOMIC_RELAXED, __HIP_MEMORY_SCOPE_AGENT);
  if (i < (B_ * D_) / 2) {                  // slot 0 <- bf16(h0), u32 pairs
    unsigned lo = (unsigned short)f2bf(h0[2 * i]);
    unsigned hi = (unsigned short)f2bf(h0[2 * i + 1]);
    __hip_atomic_store((unsigned*)Af + i, lo | (hi << 16),
                       __ATOMIC_RELAXED, __HIP_MEMORY_SCOPE_AGENT);
  }
  if (i < 64)   // cnt[16..23], winner[24], ready[25]
    __hip_atomic_store(flags + i, 0u, __ATOMIC_RELAXED, __HIP_MEMORY_SCOPE_AGENT);
  if (i < T_ * B_) {                        // idxT[t][b] = idx[b][t]
    int b = i & (B_ - 1);
    int t = i >> 5;
    idxT[i] = idx[b * T_ + t];
  }
}

// ---------- Wtb[v][d] = bf16(W_ih[d][v] + b_ih[d] + b_hh[d]) ----------
__global__ __launch_bounds__(256) void wtrans(const float* __restrict__ W,
                                              const float* __restrict__ b_ih,
                                              const float* __restrict__ b_hh,
                                              short* __restrict__ Wtb) {
  __shared__ float tile[32][33];
  const int tx = threadIdx.x & 31;
  const int ty = threadIdx.x >> 5;          // 0..7
  const int v0 = blockIdx.x * 32;
  const int d0 = blockIdx.y * 32;
#pragma unroll
  for (int i = 0; i < 32; i += 8)
    tile[ty + i][tx] = W[(size_t)(d0 + ty + i) * V_ + v0 + tx];
  __syncthreads();
  const int d = d0 + tx;
  const float bias = b_ih[d] + b_hh[d];
#pragma unroll
  for (int i = 0; i < 32; i += 8)
    Wtb[(size_t)(v0 + ty + i) * D_ + d] = f2bf(tile[tx][ty + i] + bias);
}

// ---------- persistent recurrence: R14 structure + early X-prefetch ----------
// Change vs R14/R16 (single lever): the next-step X gather (idxT + 4 Wtb
// gathers, ~L3 latency) is issued right after the poll, BEFORE the MFMA
// phase, into nxv; consumed next step. The end-of-step vmcnt(0) then drains
// only the 4 cheap sc0 h-stores instead of also the L3 gathers.
__global__ __launch_bounds__(512) void rnn_all(const short* __restrict__ Rb,
                                               const float* __restrict__ Wdiag,
                                               const float* __restrict__ h0,
                                               const short* __restrict__ Wtb,
                                               const int* __restrict__ idxT,
                                               short* __restrict__ Af,
                                               unsigned* __restrict__ flags) {
  __shared__ f32x4 part[8][2][4][64];      // 64 KB
  __shared__ int sblk;
  const int tid = threadIdx.x;

  // ---- election: first XCD bucket to seat 16 blocks wins ----
  if (tid == 0) {
    unsigned xcc;
    asm volatile("s_getreg_b32 %0, hwreg(HW_REG_XCC_ID)" : "=s"(xcc));
    xcc &= 7u;
    unsigned* cnt = flags + 16;
    unsigned* winner = flags + 24;
    unsigned rank = __hip_atomic_fetch_add(&cnt[xcc], 1u, __ATOMIC_RELAXED,
                                           __HIP_MEMORY_SCOPE_AGENT);
    int my = -1;
    if (rank == 15u) {
      unsigned exp = 0u;
      __hip_atomic_compare_exchange_strong(winner, &exp, xcc + 1u,
                                           __ATOMIC_RELAXED, __ATOMIC_RELAXED,
                                           __HIP_MEMORY_SCOPE_AGENT);
    }
    if (rank < 16u) {
      unsigned wv;
      while ((wv = __hip_atomic_load(winner, __ATOMIC_RELAXED,
                                     __HIP_MEMORY_SCOPE_AGENT)) == 0u)
        __builtin_amdgcn_s_sleep(8);
      if (wv == xcc + 1u) my = (int)rank;
    }
    sblk = my;
  }
  __syncthreads();
  const int blk = sblk;
  if (blk < 0) return;

  // drop stale replay lines from this XCD's L1/L2 BEFORE anyone stores
  __builtin_amdgcn_fence(__ATOMIC_ACQUIRE, "agent");
  if (tid == 0) {
    __hip_atomic_fetch_add(flags + 25, 1u, __ATOMIC_RELAXED, __HIP_MEMORY_SCOPE_AGENT);
    while (__hip_atomic_load(flags + 25, __ATOMIC_RELAXED,
                             __HIP_MEMORY_SCOPE_AGENT) < 16u)
      __builtin_amdgcn_s_sleep(1);
  }
  __syncthreads();

  const int lane = tid & 63;
  const int w = tid >> 6;                  // 0..7, wave-uniform
  const int n0 = blk * 64;
  const int fcol = lane & 15;
  const int l16 = lane >> 4;               // 0..3
  const int ks = w * 128;

  // persistent B fragments: Rb rows n0..n0+63, this wave's K-slice
  bf16x8 bfrag[4][4];
#pragma unroll
  for (int ni = 0; ni < 4; ++ni) {
    const short* bp = Rb + (size_t)(n0 + ni * 16 + fcol) * D_ + ks + l16 * 8;
#pragma unroll
    for (int kk = 0; kk < 4; ++kk)
      bfrag[ni][kk] = *reinterpret_cast<const bf16x8*>(bp + kk * 32);
  }

  // epilogue role: fixed (m,n) ownership across all steps
  const int mi_e = w >> 2;                 // 0..1
  const int ni_e = w & 3;                  // 0..3
  const int n_e = n0 + ni_e * 16 + fcol;
  const int mbase = mi_e * 16 + l16 * 4;   // +q -> batch row
  const float wd = Wdiag[n_e];
  float hf[4];
#pragma unroll
  for (int q = 0; q < 4; ++q)
    hf[q] = h0[(size_t)(mbase + q) * D_ + n_e];

  // X gather for step 0 (plain cached loads)
  float xv[4];
  {
    int4 tk = *reinterpret_cast<const int4*>(idxT + mbase);
    xv[0] = bf2f(*(const unsigned short*)(Wtb + (size_t)tk.x * D_ + n_e));
    xv[1] = bf2f(*(const unsigned short*)(Wtb + (size_t)tk.y * D_ + n_e));
    xv[2] = bf2f(*(const unsigned short*)(Wtb + (size_t)tk.z * D_ + n_e));
    xv[3] = bf2f(*(const unsigned short*)(Wtb + (size_t)tk.w * D_ + n_e));
  }

  for (int t = 0; t < T_; ++t) {
    // (A) sentinel-poll this wave's A-fragment of slot t (sc0, same L2)
    const size_t slot = (size_t)t * (B_ * D_);
    const short* fp0 = Af + slot + (size_t)fcol * D_ + ks + l16 * 8;
    const short* fp1 = fp0 + 16 * D_;
    U4 a[8];
    {
      int bud = 0;
      while (true) {
        load_frag_sc0(fp0, a);
        load_frag_sc0(fp1, a + 4);
        unsigned bad = 0u;
#pragma unroll
        for (int i = 0; i < 8; ++i)
#pragma unroll
          for (int j = 0; j < 4; ++j) {
            unsigned d = a[i].u[j];
            bad |= ((d & 0xFFFFu) == SENT) | ((d >> 16) == SENT);
          }
        if (!__any((int)bad)) break;
        if (++bud >= 256) {                // staleness escape: drop clean stale lines
          bud = 0;
          __builtin_amdgcn_fence(__ATOMIC_ACQUIRE, "agent");
        }
      }
    }
    bf16x8 af[2][4];
#pragma unroll
    for (int mi = 0; mi < 2; ++mi)
#pragma unroll
      for (int kk = 0; kk < 4; ++kk)
        af[mi][kk] = a[mi * 4 + kk].v;

    // (A2) EARLY next-step X prefetch: L3 latency hides under MFMA+sync+reduce
    float nxv[4] = {0.f, 0.f, 0.f, 0.f};
    if (t < T_ - 1) {
      int4 tk = *reinterpret_cast<const int4*>(idxT + (t + 1) * B_ + mbase);
      nxv[0] = bf2f(*(const unsigned short*)(Wtb + (size_t)tk.x * D_ + n_e));
      nxv[1] = bf2f(*(const unsigned short*)(Wtb + (size_t)tk.y * D_ + n_e));
      nxv[2] = bf2f(*(const unsigned short*)(Wtb + (size_t)tk.z * D_ + n_e));
      nxv[3] = bf2f(*(const unsigned short*)(Wtb + (size_t)tk.w * D_ + n_e));
    }

    // (B) MFMA partials
#pragma unroll
    for (int mi = 0; mi < 2; ++mi)
#pragma unroll
      for (int ni = 0; ni < 4; ++ni) {
        f32x4 acc = {0.f, 0.f, 0.f, 0.f};
#pragma unroll
        for (int kk = 0; kk < 4; ++kk)
          acc = __builtin_amdgcn_mfma_f32_16x16x32_bf16(af[mi][kk], bfrag[ni][kk], acc, 0, 0, 0);
        part[w][mi][ni][lane] = acc;
      }
    __syncthreads();                       // sync1: partials complete

    // (C) reduce across K-slices; tanh; publish slot t+1 (sc0 only -> local L2)
    f32x4 s = part[0][mi_e][ni_e][lane];
#pragma unroll
    for (int r = 1; r < 8; ++r) s += part[r][mi_e][ni_e][lane];

    const size_t nslot = (size_t)(t + 1) * (B_ * D_);
#pragma unroll
    for (int q2 = 0; q2 < 4; ++q2) {
      float v = fast_tanh(xv[q2] + s[q2] + hf[q2] * wd);
      hf[q2] = v;
      unsigned ov = (unsigned)(unsigned short)f2bf(v);
      short* pf = Af + nslot + (size_t)(mbase + q2) * D_ + n_e;
      asm volatile("global_store_short %0, %1, off sc0" :: "v"(pf), "v"(ov) : "memory");
    }

#pragma unroll
    for (int q2 = 0; q2 < 4; ++q2) xv[q2] = nxv[q2];

    asm volatile("s_waitcnt vmcnt(0)" ::: "memory");  // drains h-stores (L2-local)
    __syncthreads();                       // sync2: part[] reusable; data published
  }
}

// ---------- logits GEMM: bf16 C into first 16KB of each row's 32KB out-slot ----------
// XCD-aware tile swizzle: XCD x gets 256 contiguous tiles (4 M-rows) -> A-panel
// reuse becomes L2-local. nwg=2048, divisible by 8 -> bijective.
__global__ __launch_bounds__(256) void gemm_logits(const short* __restrict__ A,
                                                   const short* __restrict__ Bt,
                                                   const float* __restrict__ b_o,
                                                   short* __restrict__ Cb) {
  constexpr int K = D_;
  __shared__ __align__(16) short As[128 * 64];
  __shared__ __align__(16) short Bs[128 * 64];

  const int tid = threadIdx.x;
  const int lane = tid & 63;
  const int w = tid >> 6;
  const int wr = w >> 1, wc = w & 1;
  const int bid = blockIdx.y * 64 + blockIdx.x;      // 0..2047
  const int swz = (bid & 7) * 256 + (bid >> 3);      // XCD-contiguous tiles
  const int r0 = (swz >> 6) * 128;                   // M tile
  const int c0 = (swz & 63) * 128;                   // N tile

  f32x4 acc[4][4] = {};

  for (int k0 = 0; k0 < K; k0 += 64) {
#pragma unroll
    for (int i = 0; i < 4; ++i) {
      int c = tid + 256 * i;
      int cb = (tid & ~63) + 256 * i;
      int row = c >> 3;
      int colc = ((c & 7) ^ (row & 7)) * 8;
      lds_load16(A + (size_t)(r0 + row) * K + k0 + colc, &As[cb * 8]);
      lds_load16(Bt + (size_t)(c0 + row) * K + k0 + colc, &Bs[cb * 8]);
    }
    asm volatile("s_waitcnt vmcnt(0)" ::: "memory");
    __syncthreads();

#pragma unroll
    for (int kk = 0; kk < 2; ++kk) {
      bf16x8 af[4], bfr[4];
      const int fcol = lane & 15;
      const int chunk = (kk * 4 + (lane >> 4)) ^ (fcol & 7);
#pragma unroll
      for (int i = 0; i < 4; ++i)
        af[i] = *reinterpret_cast<const bf16x8*>(&As[(wr * 64 + i * 16 + fcol) * 64 + chunk * 8]);
#pragma unroll
      for (int j = 0; j < 4; ++j)
        bfr[j] = *reinterpret_cast<const bf16x8*>(&Bs[(wc * 64 + j * 16 + fcol) * 64 + chunk * 8]);
#pragma unroll
      for (int i = 0; i < 4; ++i)
#pragma unroll
        for (int j = 0; j < 4; ++j)
          acc[i][j] = __builtin_amdgcn_mfma_f32_16x16x32_bf16(af[i], bfr[j], acc[i][j], 0, 0, 0);
    }
    __syncthreads();
  }

  const int fcol = lane & 15;
  const int frow = (lane >> 4) * 4;
#pragma unroll
  for (int i = 0; i < 4; ++i) {
    int row = r0 + wr * 64 + i * 16 + frow;
#pragma unroll
    for (int j = 0; j < 4; ++j) {
      int col = c0 + wc * 64 + j * 16 + fcol;
      float bias = b_o[col];
#pragma unroll
      for (int q = 0; q < 4; ++q)
        Cb[(size_t)(row + q) * 16384 + col] = f2bf(acc[i][j][q] + bias);
    }
  }
}

// ---------- log-softmax: read bf16 row (first 16KB of slot), write f32 in place ----------
__global__ __launch_bounds__(256) void logsoftmax(float* __restrict__ out) {
  __shared__ float red[4];
  __shared__ float red2[4];
  const short* row = (const short*)out + (size_t)blockIdx.x * 16384;
  float* orow = out + (size_t)blockIdx.x * V_;
  const int tid = threadIdx.x;

  float v[32];
  float mx = -1e30f;
#pragma unroll
  for (int i = 0; i < 4; ++i) {
    uint4 pk = reinterpret_cast<const uint4*>(row)[i * 256 + tid];
    unsigned uu[4] = {pk.x, pk.y, pk.z, pk.w};
#pragma unroll
    for (int j = 0; j < 4; ++j) {
      float lo = bf2f((unsigned short)(uu[j] & 0xFFFFu));
      float hi = bf2f((unsigned short)(uu[j] >> 16));
      v[i * 8 + 2 * j] = lo;
      v[i * 8 + 2 * j + 1] = hi;
      mx = fmaxf(mx, fmaxf(lo, hi));
    }
  }
#pragma unroll
  for (int off = 32; off > 0; off >>= 1) mx = fmaxf(mx, __shfl_xor(mx, off, 64));
  if ((tid & 63) == 0) red[tid >> 6] = mx;
  __syncthreads();   // also orders: all bf16 reads complete before any f32 write
  mx = fmaxf(fmaxf(red[0], red[1]), fmaxf(red[2], red[3]));

  float sum = 0.f;
#pragma unroll
  for (int k = 0; k < 32; ++k) sum += expf(v[k] - mx);
#pragma unroll
  for (int off = 32; off > 0; off >>= 1) sum += __shfl_xor(sum, off, 64);
  if ((tid & 63) == 0) red2[tid >> 6] = sum;
  __syncthreads();
  sum = (red2[0] + red2[1]) + (red2[2] + red2[3]);

  const float lse = mx + logf(sum);
#pragma unroll
  for (int i = 0; i < 4; ++i) {
    float4 w1 = {v[i * 8 + 0] - lse, v[i * 8 + 1] - lse, v[i * 8 + 2] - lse, v[i * 8 + 3] - lse};
    float4 w2 = {v[i * 8 + 4] - lse, v[i * 8 + 5] - lse, v[i * 8 + 6] - lse, v[i * 8 + 7] - lse};
    *reinterpret_cast<float4*>(&orow[(i * 256 + tid) * 8]) = w1;
    *reinterpret_cast<float4*>(&orow[(i * 256 + tid) * 8 + 4]) = w2;
  }
}

extern "C" void kernel_launch(void* const* d_in, const int* in_sizes, int n_in,
                              void* d_out, int out_size, void* d_ws, size_t ws_size,
                              hipStream_t stream) {
  const int* idx = (const int*)d_in[0];
  const float* h0 = (const float*)d_in[1];
  const float* W_ih = (const float*)d_in[2];
  const float* b_ih = (const float*)d_in[3];
  const float* W_hh = (const float*)d_in[4];
  const float* b_hh = (const float*)d_in[5];
  const float* W_ho = (const float*)d_in[6];
  const float* b_o = (const float*)d_in[7];
  float* out = (float*)d_out;

  // workspace layout (~52.6 MB):
  // (unused)                  8454144 B @ 0
  // Wb  bf16 [8192][1024]    16777216 B @ 8454144
  // Rb  bf16 [1024][1024]     2097152 B @ 25231360
  // Wdiag f32 [1024]             4096 B @ 27328512
  // Wtb bf16 [8192][1024]    16777216 B @ 27332608
  // flags u32 [64] (cnt 16..23 / winner 24 / ready 25) @ 44109824
  // idxT int [128][32]          16384 B @ 44113920
  // Af  bf16 [129][32][1024]  8454144 B @ 44130304   (sc0/winner-L2 exchange)
  char* ws = (char*)d_ws;
  short* Wb = (short*)(ws + 8454144);
  short* Rb = (short*)(ws + 25231360);
  float* Wdiag = (float*)(ws + 27328512);
  short* Wtb = (short*)(ws + 27332608);
  unsigned* flags = (unsigned*)(ws + 44109824);
  int* idxT = (int*)(ws + 44113920);
  short* Af = (short*)(ws + 44130304);

  conv_bf16_k<<<dim3(8192), dim3(256), 0, stream>>>(W_ho, Wb, (V_ * D_) / 4);
  conv_whh<<<dim3(4096), dim3(256), 0, stream>>>(W_hh, Rb, Wdiag);
  prep_h<<<dim3(4096), dim3(256), 0, stream>>>(h0, idx, Af, flags, idxT);
  wtrans<<<dim3(V_ / 32, D_ / 32), dim3(256), 0, stream>>>(W_ih, b_ih, b_hh, Wtb);

  rnn_all<<<dim3(256), dim3(512), 0, stream>>>(Rb, Wdiag, h0, Wtb, idxT, Af, flags);

  // logits for step t read Af slot t+1  ->  A = Af + 32768; bf16 C into d_out slots
  gemm_logits<<<dim3(V_ / 128, (T_ * B_) / 128), dim3(256), 0, stream>>>(
      Af + B_ * D_, Wb, b_o, (short*)out);
  logsoftmax<<<dim3(T_ * B_), dim3(256), 0, stream>>>(out);
}

// Round 18
// 667.023 us; speedup vs baseline: 5.4990x; 5.4990x over previous
//
#include <hip/hip_runtime.h>
#include <hip/hip_bf16.h>
#include <cstdint>
#include <cstddef>

#define V_ 8192
#define D_ 1024
#define B_ 32
#define T_ 128
#define NBLK 16
#define SENT 0x7FC0u   // bf16 NaN — impossible tanh output

typedef __attribute__((ext_vector_type(8))) short bf16x8;
typedef __attribute__((ext_vector_type(4))) float f32x4;

__device__ __forceinline__ short f2bf(float f) {
  union { float f; unsigned u; } v; v.f = f;
  unsigned r = v.u + 0x7fffu + ((v.u >> 16) & 1u);
  return (short)(r >> 16);
}

__device__ __forceinline__ float bf2f(unsigned short u) {
  union { unsigned u; float f; } c; c.u = ((unsigned)u) << 16;
  return c.f;
}

// tanh(x) = 1 - 2/(exp2(2x*log2e)+1); exact at +/-inf, ~1e-7 abs err
__device__ __forceinline__ float fast_tanh(float x) {
  float t = __builtin_amdgcn_exp2f(x * 2.8853900817779268f);
  return 1.0f - 2.0f * __builtin_amdgcn_rcpf(t + 1.0f);
}

// async global->LDS, 16B per lane. lds base must be wave-uniform.
__device__ __forceinline__ void lds_load16(const void* g, void* l) {
  __builtin_amdgcn_global_load_lds(
      (const __attribute__((address_space(1))) unsigned int*)g,
      (__attribute__((address_space(3))) unsigned int*)l,
      16, 0, 0);
}

union U4 { int4 i4; unsigned u[4]; unsigned long long q[2]; bf16x8 v; };

// 4x dwordx4 sc0 loads (bypass L1 on miss path; served by this XCD's shared L2)
__device__ __forceinline__ void load_frag_sc0(const short* ap, U4* out) {
  asm volatile(
      "global_load_dwordx4 %0, %4, off sc0\n\t"
      "global_load_dwordx4 %1, %4, off offset:64 sc0\n\t"
      "global_load_dwordx4 %2, %4, off offset:128 sc0\n\t"
      "global_load_dwordx4 %3, %4, off offset:192 sc0\n\t"
      "s_waitcnt vmcnt(0)"
      : "=&v"(out[0].i4), "=&v"(out[1].i4), "=&v"(out[2].i4), "=&v"(out[3].i4)
      : "v"(ap) : "memory");
}

// ---------- f32 -> bf16 conversion ----------
__global__ __launch_bounds__(256) void conv_bf16_k(const float* __restrict__ in,
                                                   short* __restrict__ out, int n4) {
  int i = blockIdx.x * 256 + threadIdx.x;  // one float4 per thread
  if (i >= n4) return;
  float4 v = reinterpret_cast<const float4*>(in)[i];
  short4 o;
  o.x = f2bf(v.x); o.y = f2bf(v.y); o.z = f2bf(v.z); o.w = f2bf(v.w);
  reinterpret_cast<short4*>(out)[i] = o;
}

// ---------- W_hh split: Rb = bf16(W_hh, zero diag), Wdiag = diag(W_hh) f32 ----------
__global__ __launch_bounds__(256) void conv_whh(const float* __restrict__ W,
                                                short* __restrict__ Rb,
                                                float* __restrict__ Wdiag) {
  int i = blockIdx.x * 256 + threadIdx.x;   // over D*D = 1048576
  int n = i >> 10;
  int k = i & (D_ - 1);
  float w = W[i];
  Rb[i] = f2bf(k == n ? 0.0f : w);
  if (k == n) Wdiag[n] = w;
}

// ---------- fused: poison Af slots 1..128 + slot-0 init + flags + idxT ----------
__global__ __launch_bounds__(256) void prep_h(const float* __restrict__ h0,
                                              const int* __restrict__ idx,
                                              short* __restrict__ Af,
                                              unsigned* __restrict__ flags,
                                              int* __restrict__ idxT) {
  int i = blockIdx.x * 256 + threadIdx.x;   // 0..1048575 (u64 chunks of slots 1..128)
  __hip_atomic_store((unsigned long long*)(Af + B_ * D_) + i,
                     0x7FC07FC07FC07FC0ull, __ATOMIC_RELAXED, __HIP_MEMORY_SCOPE_AGENT);
  if (i < (B_ * D_) / 2) {                  // slot 0 <- bf16(h0), u32 pairs
    unsigned lo = (unsigned short)f2bf(h0[2 * i]);
    unsigned hi = (unsigned short)f2bf(h0[2 * i + 1]);
    __hip_atomic_store((unsigned*)Af + i, lo | (hi << 16),
                       __ATOMIC_RELAXED, __HIP_MEMORY_SCOPE_AGENT);
  }
  if (i < 64)   // cnt[16..23], winner[24], ready[25]
    __hip_atomic_store(flags + i, 0u, __ATOMIC_RELAXED, __HIP_MEMORY_SCOPE_AGENT);
  if (i < T_ * B_) {                        // idxT[t][b] = idx[b][t]
    int b = i & (B_ - 1);
    int t = i >> 5;
    idxT[i] = idx[b * T_ + t];
  }
}

// ---------- Wtb[v][d] = bf16(W_ih[d][v] + b_ih[d] + b_hh[d]) ----------
__global__ __launch_bounds__(256) void wtrans(const float* __restrict__ W,
                                              const float* __restrict__ b_ih,
                                              const float* __restrict__ b_hh,
                                              short* __restrict__ Wtb) {
  __shared__ float tile[32][33];
  const int tx = threadIdx.x & 31;
  const int ty = threadIdx.x >> 5;          // 0..7
  const int v0 = blockIdx.x * 32;
  const int d0 = blockIdx.y * 32;
#pragma unroll
  for (int i = 0; i < 32; i += 8)
    tile[ty + i][tx] = W[(size_t)(d0 + ty + i) * V_ + v0 + tx];
  __syncthreads();
  const int d = d0 + tx;
  const float bias = b_ih[d] + b_hh[d];
#pragma unroll
  for (int i = 0; i < 32; i += 8)
    Wtb[(size_t)(v0 + ty + i) * D_ + d] = f2bf(tile[tx][ty + i] + bias);
}

// ---------- persistent recurrence: R16-EXACT (proven 519 us; do not reorder) ----------
// R17 lesson: moving the X-prefetch before the MFMA phase triggered a
// staleness-escape fence storm (L2 invalidates cascading) -> 40x regression.
// Phase order poll -> MFMA -> reduce/store -> prefetch -> drain is a tuned
// equilibrium; keep it.
__global__ __launch_bounds__(512) void rnn_all(const short* __restrict__ Rb,
                                               const float* __restrict__ Wdiag,
                                               const float* __restrict__ h0,
                                               const short* __restrict__ Wtb,
                                               const int* __restrict__ idxT,
                                               short* __restrict__ Af,
                                               unsigned* __restrict__ flags) {
  __shared__ f32x4 part[8][2][4][64];      // 64 KB
  __shared__ int sblk;
  const int tid = threadIdx.x;

  // ---- election: first XCD bucket to seat 16 blocks wins ----
  if (tid == 0) {
    unsigned xcc;
    asm volatile("s_getreg_b32 %0, hwreg(HW_REG_XCC_ID)" : "=s"(xcc));
    xcc &= 7u;
    unsigned* cnt = flags + 16;
    unsigned* winner = flags + 24;
    unsigned rank = __hip_atomic_fetch_add(&cnt[xcc], 1u, __ATOMIC_RELAXED,
                                           __HIP_MEMORY_SCOPE_AGENT);
    int my = -1;
    if (rank == 15u) {
      unsigned exp = 0u;
      __hip_atomic_compare_exchange_strong(winner, &exp, xcc + 1u,
                                           __ATOMIC_RELAXED, __ATOMIC_RELAXED,
                                           __HIP_MEMORY_SCOPE_AGENT);
    }
    if (rank < 16u) {
      unsigned wv;
      while ((wv = __hip_atomic_load(winner, __ATOMIC_RELAXED,
                                     __HIP_MEMORY_SCOPE_AGENT)) == 0u)
        __builtin_amdgcn_s_sleep(8);
      if (wv == xcc + 1u) my = (int)rank;
    }
    sblk = my;
  }
  __syncthreads();
  const int blk = sblk;
  if (blk < 0) return;

  // drop stale replay lines from this XCD's L1/L2 BEFORE anyone stores
  __builtin_amdgcn_fence(__ATOMIC_ACQUIRE, "agent");
  if (tid == 0) {
    __hip_atomic_fetch_add(flags + 25, 1u, __ATOMIC_RELAXED, __HIP_MEMORY_SCOPE_AGENT);
    while (__hip_atomic_load(flags + 25, __ATOMIC_RELAXED,
                             __HIP_MEMORY_SCOPE_AGENT) < 16u)
      __builtin_amdgcn_s_sleep(1);
  }
  __syncthreads();

  const int lane = tid & 63;
  const int w = tid >> 6;                  // 0..7, wave-uniform
  const int n0 = blk * 64;
  const int fcol = lane & 15;
  const int l16 = lane >> 4;               // 0..3
  const int ks = w * 128;

  // persistent B fragments: Rb rows n0..n0+63, this wave's K-slice
  bf16x8 bfrag[4][4];
#pragma unroll
  for (int ni = 0; ni < 4; ++ni) {
    const short* bp = Rb + (size_t)(n0 + ni * 16 + fcol) * D_ + ks + l16 * 8;
#pragma unroll
    for (int kk = 0; kk < 4; ++kk)
      bfrag[ni][kk] = *reinterpret_cast<const bf16x8*>(bp + kk * 32);
  }

  // epilogue role: fixed (m,n) ownership across all steps
  const int mi_e = w >> 2;                 // 0..1
  const int ni_e = w & 3;                  // 0..3
  const int n_e = n0 + ni_e * 16 + fcol;
  const int mbase = mi_e * 16 + l16 * 4;   // +q -> batch row
  const float wd = Wdiag[n_e];
  float hf[4];
#pragma unroll
  for (int q = 0; q < 4; ++q)
    hf[q] = h0[(size_t)(mbase + q) * D_ + n_e];

  // X gather for step 0 (plain cached loads)
  float xv[4];
  {
    int4 tk = *reinterpret_cast<const int4*>(idxT + mbase);
    xv[0] = bf2f(*(const unsigned short*)(Wtb + (size_t)tk.x * D_ + n_e));
    xv[1] = bf2f(*(const unsigned short*)(Wtb + (size_t)tk.y * D_ + n_e));
    xv[2] = bf2f(*(const unsigned short*)(Wtb + (size_t)tk.z * D_ + n_e));
    xv[3] = bf2f(*(const unsigned short*)(Wtb + (size_t)tk.w * D_ + n_e));
  }

  for (int t = 0; t < T_; ++t) {
    // (A) sentinel-poll this wave's A-fragment of slot t (sc0, same L2)
    const size_t slot = (size_t)t * (B_ * D_);
    const short* fp0 = Af + slot + (size_t)fcol * D_ + ks + l16 * 8;
    const short* fp1 = fp0 + 16 * D_;
    U4 a[8];
    {
      int bud = 0;
      while (true) {
        load_frag_sc0(fp0, a);
        load_frag_sc0(fp1, a + 4);
        unsigned bad = 0u;
#pragma unroll
        for (int i = 0; i < 8; ++i)
#pragma unroll
          for (int j = 0; j < 4; ++j) {
            unsigned d = a[i].u[j];
            bad |= ((d & 0xFFFFu) == SENT) | ((d >> 16) == SENT);
          }
        if (!__any((int)bad)) break;
        if (++bud >= 256) {                // staleness escape: drop clean stale lines
          bud = 0;
          __builtin_amdgcn_fence(__ATOMIC_ACQUIRE, "agent");
        }
      }
    }
    bf16x8 af[2][4];
#pragma unroll
    for (int mi = 0; mi < 2; ++mi)
#pragma unroll
      for (int kk = 0; kk < 4; ++kk)
        af[mi][kk] = a[mi * 4 + kk].v;

    // (B) MFMA partials
#pragma unroll
    for (int mi = 0; mi < 2; ++mi)
#pragma unroll
      for (int ni = 0; ni < 4; ++ni) {
        f32x4 acc = {0.f, 0.f, 0.f, 0.f};
#pragma unroll
        for (int kk = 0; kk < 4; ++kk)
          acc = __builtin_amdgcn_mfma_f32_16x16x32_bf16(af[mi][kk], bfrag[ni][kk], acc, 0, 0, 0);
        part[w][mi][ni][lane] = acc;
      }
    __syncthreads();                       // sync1: partials complete

    // (C) reduce across K-slices; tanh; publish slot t+1 (sc0 only -> local L2)
    f32x4 s = part[0][mi_e][ni_e][lane];
#pragma unroll
    for (int r = 1; r < 8; ++r) s += part[r][mi_e][ni_e][lane];

    const size_t nslot = (size_t)(t + 1) * (B_ * D_);
#pragma unroll
    for (int q2 = 0; q2 < 4; ++q2) {
      float v = fast_tanh(xv[q2] + s[q2] + hf[q2] * wd);
      hf[q2] = v;
      unsigned ov = (unsigned)(unsigned short)f2bf(v);
      short* pf = Af + nslot + (size_t)(mbase + q2) * D_ + n_e;
      asm volatile("global_store_short %0, %1, off sc0" :: "v"(pf), "v"(ov) : "memory");
    }

    // (D) prefetch next step's X gather (plain cached loads)
    if (t < T_ - 1) {
      int4 tk = *reinterpret_cast<const int4*>(idxT + (t + 1) * B_ + mbase);
      xv[0] = bf2f(*(const unsigned short*)(Wtb + (size_t)tk.x * D_ + n_e));
      xv[1] = bf2f(*(const unsigned short*)(Wtb + (size_t)tk.y * D_ + n_e));
      xv[2] = bf2f(*(const unsigned short*)(Wtb + (size_t)tk.z * D_ + n_e));
      xv[3] = bf2f(*(const unsigned short*)(Wtb + (size_t)tk.w * D_ + n_e));
    }

    asm volatile("s_waitcnt vmcnt(0)" ::: "memory");  // sc0 stores in L2
    __syncthreads();                       // sync2: part[] reusable; data published
  }
}

// ---------- logits GEMM: bf16 C into first 16KB of each row's 32KB out-slot ----------
// XCD-aware tile swizzle: XCD x gets 256 contiguous tiles (4 M-rows) -> A-panel
// reuse becomes L2-local. nwg=2048, divisible by 8 -> bijective.
__global__ __launch_bounds__(256) void gemm_logits(const short* __restrict__ A,
                                                   const short* __restrict__ Bt,
                                                   const float* __restrict__ b_o,
                                                   short* __restrict__ Cb) {
  constexpr int K = D_;
  __shared__ __align__(16) short As[128 * 64];
  __shared__ __align__(16) short Bs[128 * 64];

  const int tid = threadIdx.x;
  const int lane = tid & 63;
  const int w = tid >> 6;
  const int wr = w >> 1, wc = w & 1;
  const int bid = blockIdx.y * 64 + blockIdx.x;      // 0..2047
  const int swz = (bid & 7) * 256 + (bid >> 3);      // XCD-contiguous tiles
  const int r0 = (swz >> 6) * 128;                   // M tile
  const int c0 = (swz & 63) * 128;                   // N tile

  f32x4 acc[4][4] = {};

  for (int k0 = 0; k0 < K; k0 += 64) {
#pragma unroll
    for (int i = 0; i < 4; ++i) {
      int c = tid + 256 * i;
      int cb = (tid & ~63) + 256 * i;
      int row = c >> 3;
      int colc = ((c & 7) ^ (row & 7)) * 8;
      lds_load16(A + (size_t)(r0 + row) * K + k0 + colc, &As[cb * 8]);
      lds_load16(Bt + (size_t)(c0 + row) * K + k0 + colc, &Bs[cb * 8]);
    }
    asm volatile("s_waitcnt vmcnt(0)" ::: "memory");
    __syncthreads();

#pragma unroll
    for (int kk = 0; kk < 2; ++kk) {
      bf16x8 af[4], bfr[4];
      const int fcol = lane & 15;
      const int chunk = (kk * 4 + (lane >> 4)) ^ (fcol & 7);
#pragma unroll
      for (int i = 0; i < 4; ++i)
        af[i] = *reinterpret_cast<const bf16x8*>(&As[(wr * 64 + i * 16 + fcol) * 64 + chunk * 8]);
#pragma unroll
      for (int j = 0; j < 4; ++j)
        bfr[j] = *reinterpret_cast<const bf16x8*>(&Bs[(wc * 64 + j * 16 + fcol) * 64 + chunk * 8]);
#pragma unroll
      for (int i = 0; i < 4; ++i)
#pragma unroll
        for (int j = 0; j < 4; ++j)
          acc[i][j] = __builtin_amdgcn_mfma_f32_16x16x32_bf16(af[i], bfr[j], acc[i][j], 0, 0, 0);
    }
    __syncthreads();
  }

  const int fcol = lane & 15;
  const int frow = (lane >> 4) * 4;
#pragma unroll
  for (int i = 0; i < 4; ++i) {
    int row = r0 + wr * 64 + i * 16 + frow;
#pragma unroll
    for (int j = 0; j < 4; ++j) {
      int col = c0 + wc * 64 + j * 16 + fcol;
      float bias = b_o[col];
#pragma unroll
      for (int q = 0; q < 4; ++q)
        Cb[(size_t)(row + q) * 16384 + col] = f2bf(acc[i][j][q] + bias);
    }
  }
}

// ---------- log-softmax: read bf16 row (first 16KB of slot), write f32 in place ----------
__global__ __launch_bounds__(256) void logsoftmax(float* __restrict__ out) {
  __shared__ float red[4];
  __shared__ float red2[4];
  const short* row = (const short*)out + (size_t)blockIdx.x * 16384;
  float* orow = out + (size_t)blockIdx.x * V_;
  const int tid = threadIdx.x;

  float v[32];
  float mx = -1e30f;
#pragma unroll
  for (int i = 0; i < 4; ++i) {
    uint4 pk = reinterpret_cast<const uint4*>(row)[i * 256 + tid];
    unsigned uu[4] = {pk.x, pk.y, pk.z, pk.w};
#pragma unroll
    for (int j = 0; j < 4; ++j) {
      float lo = bf2f((unsigned short)(uu[j] & 0xFFFFu));
      float hi = bf2f((unsigned short)(uu[j] >> 16));
      v[i * 8 + 2 * j] = lo;
      v[i * 8 + 2 * j + 1] = hi;
      mx = fmaxf(mx, fmaxf(lo, hi));
    }
  }
#pragma unroll
  for (int off = 32; off > 0; off >>= 1) mx = fmaxf(mx, __shfl_xor(mx, off, 64));
  if ((tid & 63) == 0) red[tid >> 6] = mx;
  __syncthreads();   // also orders: all bf16 reads complete before any f32 write
  mx = fmaxf(fmaxf(red[0], red[1]), fmaxf(red[2], red[3]));

  float sum = 0.f;
#pragma unroll
  for (int k = 0; k < 32; ++k) sum += expf(v[k] - mx);
#pragma unroll
  for (int off = 32; off > 0; off >>= 1) sum += __shfl_xor(sum, off, 64);
  if ((tid & 63) == 0) red2[tid >> 6] = sum;
  __syncthreads();
  sum = (red2[0] + red2[1]) + (red2[2] + red2[3]);

  const float lse = mx + logf(sum);
#pragma unroll
  for (int i = 0; i < 4; ++i) {
    float4 w1 = {v[i * 8 + 0] - lse, v[i * 8 + 1] - lse, v[i * 8 + 2] - lse, v[i * 8 + 3] - lse};
    float4 w2 = {v[i * 8 + 4] - lse, v[i * 8 + 5] - lse, v[i * 8 + 6] - lse, v[i * 8 + 7] - lse};
    *reinterpret_cast<float4*>(&orow[(i * 256 + tid) * 8]) = w1;
    *reinterpret_cast<float4*>(&orow[(i * 256 + tid) * 8 + 4]) = w2;
  }
}

extern "C" void kernel_launch(void* const* d_in, const int* in_sizes, int n_in,
                              void* d_out, int out_size, void* d_ws, size_t ws_size,
                              hipStream_t stream) {
  const int* idx = (const int*)d_in[0];
  const float* h0 = (const float*)d_in[1];
  const float* W_ih = (const float*)d_in[2];
  const float* b_ih = (const float*)d_in[3];
  const float* W_hh = (const float*)d_in[4];
  const float* b_hh = (const float*)d_in[5];
  const float* W_ho = (const float*)d_in[6];
  const float* b_o = (const float*)d_in[7];
  float* out = (float*)d_out;

  // workspace layout (~52.6 MB):
  // (unused)                  8454144 B @ 0
  // Wb  bf16 [8192][1024]    16777216 B @ 8454144
  // Rb  bf16 [1024][1024]     2097152 B @ 25231360
  // Wdiag f32 [1024]             4096 B @ 27328512
  // Wtb bf16 [8192][1024]    16777216 B @ 27332608
  // flags u32 [64] (cnt 16..23 / winner 24 / ready 25) @ 44109824
  // idxT int [128][32]          16384 B @ 44113920
  // Af  bf16 [129][32][1024]  8454144 B @ 44130304   (sc0/winner-L2 exchange)
  char* ws = (char*)d_ws;
  short* Wb = (short*)(ws + 8454144);
  short* Rb = (short*)(ws + 25231360);
  float* Wdiag = (float*)(ws + 27328512);
  short* Wtb = (short*)(ws + 27332608);
  unsigned* flags = (unsigned*)(ws + 44109824);
  int* idxT = (int*)(ws + 44113920);
  short* Af = (short*)(ws + 44130304);

  conv_bf16_k<<<dim3(8192), dim3(256), 0, stream>>>(W_ho, Wb, (V_ * D_) / 4);
  conv_whh<<<dim3(4096), dim3(256), 0, stream>>>(W_hh, Rb, Wdiag);
  prep_h<<<dim3(4096), dim3(256), 0, stream>>>(h0, idx, Af, flags, idxT);
  wtrans<<<dim3(V_ / 32, D_ / 32), dim3(256), 0, stream>>>(W_ih, b_ih, b_hh, Wtb);

  rnn_all<<<dim3(256), dim3(512), 0, stream>>>(Rb, Wdiag, h0, Wtb, idxT, Af, flags);

  // logits for step t read Af slot t+1  ->  A = Af + 32768; bf16 C into d_out slots
  gemm_logits<<<dim3(V_ / 128, (T_ * B_) / 128), dim3(256), 0, stream>>>(
      Af + B_ * D_, Wb, b_o, (short*)out);
  logsoftmax<<<dim3(T_ * B_), dim3(256), 0, stream>>>(out);
}

// Round 19
// 666.139 us; speedup vs baseline: 5.5063x; 1.0013x over previous
//
#include <hip/hip_runtime.h>
#include <hip/hip_bf16.h>
#include <cstdint>
#include <cstddef>

#define V_ 8192
#define D_ 1024
#define B_ 32
#define T_ 128
#define NBLK 16
#define SENT 0x7FC0u   // bf16 NaN — impossible tanh output

typedef __attribute__((ext_vector_type(8))) short bf16x8;
typedef __attribute__((ext_vector_type(4))) float f32x4;

__device__ __forceinline__ short f2bf(float f) {
  union { float f; unsigned u; } v; v.f = f;
  unsigned r = v.u + 0x7fffu + ((v.u >> 16) & 1u);
  return (short)(r >> 16);
}

__device__ __forceinline__ float bf2f(unsigned short u) {
  union { unsigned u; float f; } c; c.u = ((unsigned)u) << 16;
  return c.f;
}

// tanh(x) = 1 - 2/(exp2(2x*log2e)+1); exact at +/-inf, ~1e-7 abs err
__device__ __forceinline__ float fast_tanh(float x) {
  float t = __builtin_amdgcn_exp2f(x * 2.8853900817779268f);
  return 1.0f - 2.0f * __builtin_amdgcn_rcpf(t + 1.0f);
}

// async global->LDS, 16B per lane. lds base must be wave-uniform.
__device__ __forceinline__ void lds_load16(const void* g, void* l) {
  __builtin_amdgcn_global_load_lds(
      (const __attribute__((address_space(1))) unsigned int*)g,
      (__attribute__((address_space(3))) unsigned int*)l,
      16, 0, 0);
}

union U4 { int4 i4; unsigned u[4]; unsigned long long q[2]; bf16x8 v; };

// 4x dwordx4 sc0 loads (bypass L1 on miss path; served by this XCD's shared L2)
__device__ __forceinline__ void load_frag_sc0(const short* ap, U4* out) {
  asm volatile(
      "global_load_dwordx4 %0, %4, off sc0\n\t"
      "global_load_dwordx4 %1, %4, off offset:64 sc0\n\t"
      "global_load_dwordx4 %2, %4, off offset:128 sc0\n\t"
      "global_load_dwordx4 %3, %4, off offset:192 sc0\n\t"
      "s_waitcnt vmcnt(0)"
      : "=&v"(out[0].i4), "=&v"(out[1].i4), "=&v"(out[2].i4), "=&v"(out[3].i4)
      : "v"(ap) : "memory");
}

// ---------- fused preamble: Rb/Wdiag split + Af poison/init + flags + idxT ----------
__global__ __launch_bounds__(256) void prep2(const float* __restrict__ W,
                                             const float* __restrict__ h0,
                                             const int* __restrict__ idx,
                                             short* __restrict__ Rb,
                                             float* __restrict__ Wdiag,
                                             short* __restrict__ Af,
                                             unsigned* __restrict__ flags,
                                             int* __restrict__ idxT) {
  int i = blockIdx.x * 256 + threadIdx.x;   // 0..1048575
  // W_hh split
  {
    int n = i >> 10;
    int k = i & (D_ - 1);
    float w = W[i];
    Rb[i] = f2bf(k == n ? 0.0f : w);
    if (k == n) Wdiag[n] = w;
  }
  // poison Af slots 1..128 (u64 chunks)
  __hip_atomic_store((unsigned long long*)(Af + B_ * D_) + i,
                     0x7FC07FC07FC07FC0ull, __ATOMIC_RELAXED, __HIP_MEMORY_SCOPE_AGENT);
  if (i < (B_ * D_) / 2) {                  // slot 0 <- bf16(h0), u32 pairs
    unsigned lo = (unsigned short)f2bf(h0[2 * i]);
    unsigned hi = (unsigned short)f2bf(h0[2 * i + 1]);
    __hip_atomic_store((unsigned*)Af + i, lo | (hi << 16),
                       __ATOMIC_RELAXED, __HIP_MEMORY_SCOPE_AGENT);
  }
  if (i < 64)   // cnt[16..23], winner[24], ready[25], workq ctr[26]
    __hip_atomic_store(flags + i, 0u, __ATOMIC_RELAXED, __HIP_MEMORY_SCOPE_AGENT);
  if (i < T_ * B_) {                        // idxT[t][b] = idx[b][t]
    int b = i & (B_ - 1);
    int t = i >> 5;
    idxT[i] = idx[b * T_ + t];
  }
}

// ---------- Wtb[v][d] = bf16(W_ih[d][v] + b_ih[d] + b_hh[d]) ----------
__global__ __launch_bounds__(256) void wtrans(const float* __restrict__ W,
                                              const float* __restrict__ b_ih,
                                              const float* __restrict__ b_hh,
                                              short* __restrict__ Wtb) {
  __shared__ float tile[32][33];
  const int tx = threadIdx.x & 31;
  const int ty = threadIdx.x >> 5;          // 0..7
  const int v0 = blockIdx.x * 32;
  const int d0 = blockIdx.y * 32;
#pragma unroll
  for (int i = 0; i < 32; i += 8)
    tile[ty + i][tx] = W[(size_t)(d0 + ty + i) * V_ + v0 + tx];
  __syncthreads();
  const int d = d0 + tx;
  const float bias = b_ih[d] + b_hh[d];
#pragma unroll
  for (int i = 0; i < 32; i += 8)
    Wtb[(size_t)(v0 + ty + i) * D_ + d] = f2bf(tile[tx][ty + i] + bias);
}

// ---------- persistent recurrence: R16-EXACT participant path ----------
// Non-elected blocks (240 of 256) convert W_ho->Wb (needed only by the later
// gemm) via an atomic work-queue, hidden in the shadow of the recurrence.
// R17 lesson: the participant loop's phase order is a tuned equilibrium; the
// shadow work touches neither its phases nor (materially) its L2 window.
__global__ __launch_bounds__(512) void rnn_all(const short* __restrict__ Rb,
                                               const float* __restrict__ Wdiag,
                                               const float* __restrict__ h0,
                                               const short* __restrict__ Wtb,
                                               const int* __restrict__ idxT,
                                               short* __restrict__ Af,
                                               unsigned* __restrict__ flags,
                                               const float* __restrict__ W_ho,
                                               short* __restrict__ Wb) {
  __shared__ f32x4 part[8][2][4][64];      // 64 KB
  __shared__ int sblk;
  __shared__ unsigned schunk;
  const int tid = threadIdx.x;

  // ---- election: first XCD bucket to seat 16 blocks wins ----
  if (tid == 0) {
    unsigned xcc;
    asm volatile("s_getreg_b32 %0, hwreg(HW_REG_XCC_ID)" : "=s"(xcc));
    xcc &= 7u;
    unsigned* cnt = flags + 16;
    unsigned* winner = flags + 24;
    unsigned rank = __hip_atomic_fetch_add(&cnt[xcc], 1u, __ATOMIC_RELAXED,
                                           __HIP_MEMORY_SCOPE_AGENT);
    int my = -1;
    if (rank == 15u) {
      unsigned exp = 0u;
      __hip_atomic_compare_exchange_strong(winner, &exp, xcc + 1u,
                                           __ATOMIC_RELAXED, __ATOMIC_RELAXED,
                                           __HIP_MEMORY_SCOPE_AGENT);
    }
    if (rank < 16u) {
      unsigned wv;
      while ((wv = __hip_atomic_load(winner, __ATOMIC_RELAXED,
                                     __HIP_MEMORY_SCOPE_AGENT)) == 0u)
        __builtin_amdgcn_s_sleep(8);
      if (wv == xcc + 1u) my = (int)rank;
    }
    sblk = my;
  }
  __syncthreads();
  const int blk = sblk;

  if (blk < 0) {
    // ===== shadow work: W_ho -> Wb (bf16), atomic work-queue =====
    while (true) {
      if (tid == 0)
        schunk = __hip_atomic_fetch_add(flags + 26, 1u, __ATOMIC_RELAXED,
                                        __HIP_MEMORY_SCOPE_AGENT);
      __syncthreads();
      unsigned c = schunk;
      __syncthreads();
      if (c >= 1024u) return;              // 1024 chunks x 2048 float4 = 2M
#pragma unroll
      for (int r = 0; r < 4; ++r) {
        int i = (int)c * 2048 + r * 512 + tid;
        float4 v = reinterpret_cast<const float4*>(W_ho)[i];
        short4 o;
        o.x = f2bf(v.x); o.y = f2bf(v.y); o.z = f2bf(v.z); o.w = f2bf(v.w);
        reinterpret_cast<short4*>(Wb)[i] = o;
      }
    }
  }

  // drop stale replay lines from this XCD's L1/L2 BEFORE anyone stores
  __builtin_amdgcn_fence(__ATOMIC_ACQUIRE, "agent");
  if (tid == 0) {
    __hip_atomic_fetch_add(flags + 25, 1u, __ATOMIC_RELAXED, __HIP_MEMORY_SCOPE_AGENT);
    while (__hip_atomic_load(flags + 25, __ATOMIC_RELAXED,
                             __HIP_MEMORY_SCOPE_AGENT) < 16u)
      __builtin_amdgcn_s_sleep(1);
  }
  __syncthreads();

  const int lane = tid & 63;
  const int w = tid >> 6;                  // 0..7, wave-uniform
  const int n0 = blk * 64;
  const int fcol = lane & 15;
  const int l16 = lane >> 4;               // 0..3
  const int ks = w * 128;

  // persistent B fragments: Rb rows n0..n0+63, this wave's K-slice
  bf16x8 bfrag[4][4];
#pragma unroll
  for (int ni = 0; ni < 4; ++ni) {
    const short* bp = Rb + (size_t)(n0 + ni * 16 + fcol) * D_ + ks + l16 * 8;
#pragma unroll
    for (int kk = 0; kk < 4; ++kk)
      bfrag[ni][kk] = *reinterpret_cast<const bf16x8*>(bp + kk * 32);
  }

  // epilogue role: fixed (m,n) ownership across all steps
  const int mi_e = w >> 2;                 // 0..1
  const int ni_e = w & 3;                  // 0..3
  const int n_e = n0 + ni_e * 16 + fcol;
  const int mbase = mi_e * 16 + l16 * 4;   // +q -> batch row
  const float wd = Wdiag[n_e];
  float hf[4];
#pragma unroll
  for (int q = 0; q < 4; ++q)
    hf[q] = h0[(size_t)(mbase + q) * D_ + n_e];

  // X gather for step 0 (plain cached loads)
  float xv[4];
  {
    int4 tk = *reinterpret_cast<const int4*>(idxT + mbase);
    xv[0] = bf2f(*(const unsigned short*)(Wtb + (size_t)tk.x * D_ + n_e));
    xv[1] = bf2f(*(const unsigned short*)(Wtb + (size_t)tk.y * D_ + n_e));
    xv[2] = bf2f(*(const unsigned short*)(Wtb + (size_t)tk.z * D_ + n_e));
    xv[3] = bf2f(*(const unsigned short*)(Wtb + (size_t)tk.w * D_ + n_e));
  }

  for (int t = 0; t < T_; ++t) {
    // (A) sentinel-poll this wave's A-fragment of slot t (sc0, same L2)
    const size_t slot = (size_t)t * (B_ * D_);
    const short* fp0 = Af + slot + (size_t)fcol * D_ + ks + l16 * 8;
    const short* fp1 = fp0 + 16 * D_;
    U4 a[8];
    {
      int bud = 0;
      while (true) {
        load_frag_sc0(fp0, a);
        load_frag_sc0(fp1, a + 4);
        unsigned bad = 0u;
#pragma unroll
        for (int i = 0; i < 8; ++i)
#pragma unroll
          for (int j = 0; j < 4; ++j) {
            unsigned d = a[i].u[j];
            bad |= ((d & 0xFFFFu) == SENT) | ((d >> 16) == SENT);
          }
        if (!__any((int)bad)) break;
        if (++bud >= 256) {                // staleness escape: drop clean stale lines
          bud = 0;
          __builtin_amdgcn_fence(__ATOMIC_ACQUIRE, "agent");
        }
      }
    }
    bf16x8 af[2][4];
#pragma unroll
    for (int mi = 0; mi < 2; ++mi)
#pragma unroll
      for (int kk = 0; kk < 4; ++kk)
        af[mi][kk] = a[mi * 4 + kk].v;

    // (B) MFMA partials
#pragma unroll
    for (int mi = 0; mi < 2; ++mi)
#pragma unroll
      for (int ni = 0; ni < 4; ++ni) {
        f32x4 acc = {0.f, 0.f, 0.f, 0.f};
#pragma unroll
        for (int kk = 0; kk < 4; ++kk)
          acc = __builtin_amdgcn_mfma_f32_16x16x32_bf16(af[mi][kk], bfrag[ni][kk], acc, 0, 0, 0);
        part[w][mi][ni][lane] = acc;
      }
    __syncthreads();                       // sync1: partials complete

    // (C) reduce across K-slices; tanh; publish slot t+1 (sc0 only -> local L2)
    f32x4 s = part[0][mi_e][ni_e][lane];
#pragma unroll
    for (int r = 1; r < 8; ++r) s += part[r][mi_e][ni_e][lane];

    const size_t nslot = (size_t)(t + 1) * (B_ * D_);
#pragma unroll
    for (int q2 = 0; q2 < 4; ++q2) {
      float v = fast_tanh(xv[q2] + s[q2] + hf[q2] * wd);
      hf[q2] = v;
      unsigned ov = (unsigned)(unsigned short)f2bf(v);
      short* pf = Af + nslot + (size_t)(mbase + q2) * D_ + n_e;
      asm volatile("global_store_short %0, %1, off sc0" :: "v"(pf), "v"(ov) : "memory");
    }

    // (D) prefetch next step's X gather (plain cached loads)
    if (t < T_ - 1) {
      int4 tk = *reinterpret_cast<const int4*>(idxT + (t + 1) * B_ + mbase);
      xv[0] = bf2f(*(const unsigned short*)(Wtb + (size_t)tk.x * D_ + n_e));
      xv[1] = bf2f(*(const unsigned short*)(Wtb + (size_t)tk.y * D_ + n_e));
      xv[2] = bf2f(*(const unsigned short*)(Wtb + (size_t)tk.z * D_ + n_e));
      xv[3] = bf2f(*(const unsigned short*)(Wtb + (size_t)tk.w * D_ + n_e));
    }

    asm volatile("s_waitcnt vmcnt(0)" ::: "memory");  // sc0 stores in L2
    __syncthreads();                       // sync2: part[] reusable; data published
  }
}

// ---------- logits GEMM: bf16 C into first 16KB of each row's 32KB out-slot ----------
__global__ __launch_bounds__(256) void gemm_logits(const short* __restrict__ A,
                                                   const short* __restrict__ Bt,
                                                   const float* __restrict__ b_o,
                                                   short* __restrict__ Cb) {
  constexpr int K = D_;
  __shared__ __align__(16) short As[128 * 64];
  __shared__ __align__(16) short Bs[128 * 64];

  const int tid = threadIdx.x;
  const int lane = tid & 63;
  const int w = tid >> 6;
  const int wr = w >> 1, wc = w & 1;
  const int r0 = blockIdx.y * 128;
  const int c0 = blockIdx.x * 128;

  f32x4 acc[4][4] = {};

  for (int k0 = 0; k0 < K; k0 += 64) {
#pragma unroll
    for (int i = 0; i < 4; ++i) {
      int c = tid + 256 * i;
      int cb = (tid & ~63) + 256 * i;
      int row = c >> 3;
      int colc = ((c & 7) ^ (row & 7)) * 8;
      lds_load16(A + (size_t)(r0 + row) * K + k0 + colc, &As[cb * 8]);
      lds_load16(Bt + (size_t)(c0 + row) * K + k0 + colc, &Bs[cb * 8]);
    }
    asm volatile("s_waitcnt vmcnt(0)" ::: "memory");
    __syncthreads();

#pragma unroll
    for (int kk = 0; kk < 2; ++kk) {
      bf16x8 af[4], bfr[4];
      const int fcol = lane & 15;
      const int chunk = (kk * 4 + (lane >> 4)) ^ (fcol & 7);
#pragma unroll
      for (int i = 0; i < 4; ++i)
        af[i] = *reinterpret_cast<const bf16x8*>(&As[(wr * 64 + i * 16 + fcol) * 64 + chunk * 8]);
#pragma unroll
      for (int j = 0; j < 4; ++j)
        bfr[j] = *reinterpret_cast<const bf16x8*>(&Bs[(wc * 64 + j * 16 + fcol) * 64 + chunk * 8]);
#pragma unroll
      for (int i = 0; i < 4; ++i)
#pragma unroll
        for (int j = 0; j < 4; ++j)
          acc[i][j] = __builtin_amdgcn_mfma_f32_16x16x32_bf16(af[i], bfr[j], acc[i][j], 0, 0, 0);
    }
    __syncthreads();
  }

  const int fcol = lane & 15;
  const int frow = (lane >> 4) * 4;
#pragma unroll
  for (int i = 0; i < 4; ++i) {
    int row = r0 + wr * 64 + i * 16 + frow;
#pragma unroll
    for (int j = 0; j < 4; ++j) {
      int col = c0 + wc * 64 + j * 16 + fcol;
      float bias = b_o[col];
#pragma unroll
      for (int q = 0; q < 4; ++q)
        Cb[(size_t)(row + q) * 16384 + col] = f2bf(acc[i][j][q] + bias);
    }
  }
}

// ---------- log-softmax: read bf16 row (first 16KB of slot), write f32 in place ----------
__global__ __launch_bounds__(256) void logsoftmax(float* __restrict__ out) {
  __shared__ float red[4];
  __shared__ float red2[4];
  const short* row = (const short*)out + (size_t)blockIdx.x * 16384;
  float* orow = out + (size_t)blockIdx.x * V_;
  const int tid = threadIdx.x;

  float v[32];
  float mx = -1e30f;
#pragma unroll
  for (int i = 0; i < 4; ++i) {
    uint4 pk = reinterpret_cast<const uint4*>(row)[i * 256 + tid];
    unsigned uu[4] = {pk.x, pk.y, pk.z, pk.w};
#pragma unroll
    for (int j = 0; j < 4; ++j) {
      float lo = bf2f((unsigned short)(uu[j] & 0xFFFFu));
      float hi = bf2f((unsigned short)(uu[j] >> 16));
      v[i * 8 + 2 * j] = lo;
      v[i * 8 + 2 * j + 1] = hi;
      mx = fmaxf(mx, fmaxf(lo, hi));
    }
  }
#pragma unroll
  for (int off = 32; off > 0; off >>= 1) mx = fmaxf(mx, __shfl_xor(mx, off, 64));
  if ((tid & 63) == 0) red[tid >> 6] = mx;
  __syncthreads();   // also orders: all bf16 reads complete before any f32 write
  mx = fmaxf(fmaxf(red[0], red[1]), fmaxf(red[2], red[3]));

  float sum = 0.f;
#pragma unroll
  for (int k = 0; k < 32; ++k) sum += expf(v[k] - mx);
#pragma unroll
  for (int off = 32; off > 0; off >>= 1) sum += __shfl_xor(sum, off, 64);
  if ((tid & 63) == 0) red2[tid >> 6] = sum;
  __syncthreads();
  sum = (red2[0] + red2[1]) + (red2[2] + red2[3]);

  const float lse = mx + logf(sum);
#pragma unroll
  for (int i = 0; i < 4; ++i) {
    float4 w1 = {v[i * 8 + 0] - lse, v[i * 8 + 1] - lse, v[i * 8 + 2] - lse, v[i * 8 + 3] - lse};
    float4 w2 = {v[i * 8 + 4] - lse, v[i * 8 + 5] - lse, v[i * 8 + 6] - lse, v[i * 8 + 7] - lse};
    *reinterpret_cast<float4*>(&orow[(i * 256 + tid) * 8]) = w1;
    *reinterpret_cast<float4*>(&orow[(i * 256 + tid) * 8 + 4]) = w2;
  }
}

extern "C" void kernel_launch(void* const* d_in, const int* in_sizes, int n_in,
                              void* d_out, int out_size, void* d_ws, size_t ws_size,
                              hipStream_t stream) {
  const int* idx = (const int*)d_in[0];
  const float* h0 = (const float*)d_in[1];
  const float* W_ih = (const float*)d_in[2];
  const float* b_ih = (const float*)d_in[3];
  const float* W_hh = (const float*)d_in[4];
  const float* b_hh = (const float*)d_in[5];
  const float* W_ho = (const float*)d_in[6];
  const float* b_o = (const float*)d_in[7];
  float* out = (float*)d_out;

  // workspace layout (~52.6 MB):
  // (unused)                  8454144 B @ 0
  // Wb  bf16 [8192][1024]    16777216 B @ 8454144
  // Rb  bf16 [1024][1024]     2097152 B @ 25231360
  // Wdiag f32 [1024]             4096 B @ 27328512
  // Wtb bf16 [8192][1024]    16777216 B @ 27332608
  // flags u32 [64] (cnt 16..23 / winner 24 / ready 25 / workq 26) @ 44109824
  // idxT int [128][32]          16384 B @ 44113920
  // Af  bf16 [129][32][1024]  8454144 B @ 44130304   (sc0/winner-L2 exchange)
  char* ws = (char*)d_ws;
  short* Wb = (short*)(ws + 8454144);
  short* Rb = (short*)(ws + 25231360);
  float* Wdiag = (float*)(ws + 27328512);
  short* Wtb = (short*)(ws + 27332608);
  unsigned* flags = (unsigned*)(ws + 44109824);
  int* idxT = (int*)(ws + 44113920);
  short* Af = (short*)(ws + 44130304);

  prep2<<<dim3(4096), dim3(256), 0, stream>>>(W_hh, h0, idx, Rb, Wdiag, Af, flags, idxT);
  wtrans<<<dim3(V_ / 32, D_ / 32), dim3(256), 0, stream>>>(W_ih, b_ih, b_hh, Wtb);

  rnn_all<<<dim3(256), dim3(512), 0, stream>>>(Rb, Wdiag, h0, Wtb, idxT, Af, flags,
                                               W_ho, Wb);

  // logits for step t read Af slot t+1  ->  A = Af + 32768; bf16 C into d_out slots
  gemm_logits<<<dim3(V_ / 128, (T_ * B_) / 128), dim3(256), 0, stream>>>(
      Af + B_ * D_, Wb, b_o, (short*)out);
  logsoftmax<<<dim3(T_ * B_), dim3(256), 0, stream>>>(out);
}

// Round 20
// 656.480 us; speedup vs baseline: 5.5873x; 1.0147x over previous
//
#include <hip/hip_runtime.h>
#include <hip/hip_bf16.h>
#include <cstdint>
#include <cstddef>

#define V_ 8192
#define D_ 1024
#define B_ 32
#define T_ 128
#define NBLK 16
#define SENT 0x7FC0u   // bf16 NaN — impossible tanh output

typedef __attribute__((ext_vector_type(8))) short bf16x8;
typedef __attribute__((ext_vector_type(4))) float f32x4;

__device__ __forceinline__ short f2bf(float f) {
  union { float f; unsigned u; } v; v.f = f;
  unsigned r = v.u + 0x7fffu + ((v.u >> 16) & 1u);
  return (short)(r >> 16);
}

__device__ __forceinline__ float bf2f(unsigned short u) {
  union { unsigned u; float f; } c; c.u = ((unsigned)u) << 16;
  return c.f;
}

// tanh(x) = 1 - 2/(exp2(2x*log2e)+1); exact at +/-inf, ~1e-7 abs err
__device__ __forceinline__ float fast_tanh(float x) {
  float t = __builtin_amdgcn_exp2f(x * 2.8853900817779268f);
  return 1.0f - 2.0f * __builtin_amdgcn_rcpf(t + 1.0f);
}

// async global->LDS, 16B per lane. lds base must be wave-uniform.
__device__ __forceinline__ void lds_load16(const void* g, void* l) {
  __builtin_amdgcn_global_load_lds(
      (const __attribute__((address_space(1))) unsigned int*)g,
      (__attribute__((address_space(3))) unsigned int*)l,
      16, 0, 0);
}

union U4 { int4 i4; unsigned u[4]; unsigned long long q[2]; bf16x8 v; };

// 4x dwordx4 sc0 loads (bypass L1 on miss path; served by this XCD's shared L2)
__device__ __forceinline__ void load_frag_sc0(const short* ap, U4* out) {
  asm volatile(
      "global_load_dwordx4 %0, %4, off sc0\n\t"
      "global_load_dwordx4 %1, %4, off offset:64 sc0\n\t"
      "global_load_dwordx4 %2, %4, off offset:128 sc0\n\t"
      "global_load_dwordx4 %3, %4, off offset:192 sc0\n\t"
      "s_waitcnt vmcnt(0)"
      : "=&v"(out[0].i4), "=&v"(out[1].i4), "=&v"(out[2].i4), "=&v"(out[3].i4)
      : "v"(ap) : "memory");
}

// ---------- f32 -> bf16 conversion ----------
__global__ __launch_bounds__(256) void conv_bf16_k(const float* __restrict__ in,
                                                   short* __restrict__ out, int n4) {
  int i = blockIdx.x * 256 + threadIdx.x;  // one float4 per thread
  if (i >= n4) return;
  float4 v = reinterpret_cast<const float4*>(in)[i];
  short4 o;
  o.x = f2bf(v.x); o.y = f2bf(v.y); o.z = f2bf(v.z); o.w = f2bf(v.w);
  reinterpret_cast<short4*>(out)[i] = o;
}

// ---------- W_hh split: Rb = bf16(W_hh, zero diag), Wdiag = diag(W_hh) f32 ----------
__global__ __launch_bounds__(256) void conv_whh(const float* __restrict__ W,
                                                short* __restrict__ Rb,
                                                float* __restrict__ Wdiag) {
  int i = blockIdx.x * 256 + threadIdx.x;   // over D*D = 1048576
  int n = i >> 10;
  int k = i & (D_ - 1);
  float w = W[i];
  Rb[i] = f2bf(k == n ? 0.0f : w);
  if (k == n) Wdiag[n] = w;
}

// ---------- poison Af slots 1..128 with bf16-NaN sentinel (agent stores -> LLC) ----------
__global__ __launch_bounds__(256) void poison_h(unsigned long long* __restrict__ p, int n8) {
  int i = blockIdx.x * 256 + threadIdx.x;   // u64 chunks
  if (i < n8)
    __hip_atomic_store(p + i, 0x7FC07FC07FC07FC0ull,
                       __ATOMIC_RELAXED, __HIP_MEMORY_SCOPE_AGENT);
}

// ---------- h0 -> Af slot0 (agent); election vars zeroed; transpose idx ----------
__global__ __launch_bounds__(256) void init_h(const float* __restrict__ h0,
                                              const int* __restrict__ idx,
                                              short* __restrict__ Af0,
                                              unsigned* __restrict__ flags,
                                              int* __restrict__ idxT) {
  int i = blockIdx.x * 256 + threadIdx.x;   // over 16384 (u32 pairs)
  if (i < (B_ * D_) / 2) {
    unsigned lo = (unsigned short)f2bf(h0[2 * i]);
    unsigned hi = (unsigned short)f2bf(h0[2 * i + 1]);
    __hip_atomic_store((unsigned*)Af0 + i, lo | (hi << 16),
                       __ATOMIC_RELAXED, __HIP_MEMORY_SCOPE_AGENT);
  }
  if (i < 64)   // cnt[16..23], winner[24], ready[25]
    __hip_atomic_store(flags + i, 0u, __ATOMIC_RELAXED, __HIP_MEMORY_SCOPE_AGENT);
  if (i < T_ * B_) {                        // idxT[t][b] = idx[b][t]
    int b = i & (B_ - 1);
    int t = i >> 5;
    idxT[i] = idx[b * T_ + t];
  }
}

// ---------- Wtb[v][d] = bf16(W_ih[d][v] + b_ih[d] + b_hh[d]) ----------
__global__ __launch_bounds__(256) void wtrans(const float* __restrict__ W,
                                              const float* __restrict__ b_ih,
                                              const float* __restrict__ b_hh,
                                              short* __restrict__ Wtb) {
  __shared__ float tile[32][33];
  const int tx = threadIdx.x & 31;
  const int ty = threadIdx.x >> 5;          // 0..7
  const int v0 = blockIdx.x * 32;
  const int d0 = blockIdx.y * 32;
#pragma unroll
  for (int i = 0; i < 32; i += 8)
    tile[ty + i][tx] = W[(size_t)(d0 + ty + i) * V_ + v0 + tx];
  __syncthreads();
  const int d = d0 + tx;
  const float bias = b_ih[d] + b_hh[d];
#pragma unroll
  for (int i = 0; i < 32; i += 8)
    Wtb[(size_t)(v0 + ty + i) * D_ + d] = f2bf(tile[tx][ty + i] + bias);
}

// ---------- persistent recurrence: R16-EXACT (proven 519 us; do not perturb) ----------
// Converged equilibrium: 16 XCD-colocated blocks, sc0-only exchange through the
// winner XCD's L2, sentinel dataflow (2048-line spread), escape fence as a
// last-resort valve. R17/R19 lessons: phase reordering or background traffic
// trips the escape valve into a fence storm -- keep this loop isolated.
__global__ __launch_bounds__(512) void rnn_all(const short* __restrict__ Rb,
                                               const float* __restrict__ Wdiag,
                                               const float* __restrict__ h0,
                                               const short* __restrict__ Wtb,
                                               const int* __restrict__ idxT,
                                               short* __restrict__ Af,
                                               unsigned* __restrict__ flags) {
  __shared__ f32x4 part[8][2][4][64];      // 64 KB
  __shared__ int sblk;
  const int tid = threadIdx.x;

  // ---- election: first XCD bucket to seat 16 blocks wins ----
  if (tid == 0) {
    unsigned xcc;
    asm volatile("s_getreg_b32 %0, hwreg(HW_REG_XCC_ID)" : "=s"(xcc));
    xcc &= 7u;
    unsigned* cnt = flags + 16;
    unsigned* winner = flags + 24;
    unsigned rank = __hip_atomic_fetch_add(&cnt[xcc], 1u, __ATOMIC_RELAXED,
                                           __HIP_MEMORY_SCOPE_AGENT);
    int my = -1;
    if (rank == 15u) {
      unsigned exp = 0u;
      __hip_atomic_compare_exchange_strong(winner, &exp, xcc + 1u,
                                           __ATOMIC_RELAXED, __ATOMIC_RELAXED,
                                           __HIP_MEMORY_SCOPE_AGENT);
    }
    if (rank < 16u) {
      unsigned wv;
      while ((wv = __hip_atomic_load(winner, __ATOMIC_RELAXED,
                                     __HIP_MEMORY_SCOPE_AGENT)) == 0u)
        __builtin_amdgcn_s_sleep(8);
      if (wv == xcc + 1u) my = (int)rank;
    }
    sblk = my;
  }
  __syncthreads();
  const int blk = sblk;
  if (blk < 0) return;

  // drop stale replay lines from this XCD's L1/L2 BEFORE anyone stores
  __builtin_amdgcn_fence(__ATOMIC_ACQUIRE, "agent");
  if (tid == 0) {
    __hip_atomic_fetch_add(flags + 25, 1u, __ATOMIC_RELAXED, __HIP_MEMORY_SCOPE_AGENT);
    while (__hip_atomic_load(flags + 25, __ATOMIC_RELAXED,
                             __HIP_MEMORY_SCOPE_AGENT) < 16u)
      __builtin_amdgcn_s_sleep(1);
  }
  __syncthreads();

  const int lane = tid & 63;
  const int w = tid >> 6;                  // 0..7, wave-uniform
  const int n0 = blk * 64;
  const int fcol = lane & 15;
  const int l16 = lane >> 4;               // 0..3
  const int ks = w * 128;

  // persistent B fragments: Rb rows n0..n0+63, this wave's K-slice
  bf16x8 bfrag[4][4];
#pragma unroll
  for (int ni = 0; ni < 4; ++ni) {
    const short* bp = Rb + (size_t)(n0 + ni * 16 + fcol) * D_ + ks + l16 * 8;
#pragma unroll
    for (int kk = 0; kk < 4; ++kk)
      bfrag[ni][kk] = *reinterpret_cast<const bf16x8*>(bp + kk * 32);
  }

  // epilogue role: fixed (m,n) ownership across all steps
  const int mi_e = w >> 2;                 // 0..1
  const int ni_e = w & 3;                  // 0..3
  const int n_e = n0 + ni_e * 16 + fcol;
  const int mbase = mi_e * 16 + l16 * 4;   // +q -> batch row
  const float wd = Wdiag[n_e];
  float hf[4];
#pragma unroll
  for (int q = 0; q < 4; ++q)
    hf[q] = h0[(size_t)(mbase + q) * D_ + n_e];

  // X gather for step 0 (plain cached loads)
  float xv[4];
  {
    int4 tk = *reinterpret_cast<const int4*>(idxT + mbase);
    xv[0] = bf2f(*(const unsigned short*)(Wtb + (size_t)tk.x * D_ + n_e));
    xv[1] = bf2f(*(const unsigned short*)(Wtb + (size_t)tk.y * D_ + n_e));
    xv[2] = bf2f(*(const unsigned short*)(Wtb + (size_t)tk.z * D_ + n_e));
    xv[3] = bf2f(*(const unsigned short*)(Wtb + (size_t)tk.w * D_ + n_e));
  }

  for (int t = 0; t < T_; ++t) {
    // (A) sentinel-poll this wave's A-fragment of slot t (sc0, same L2)
    const size_t slot = (size_t)t * (B_ * D_);
    const short* fp0 = Af + slot + (size_t)fcol * D_ + ks + l16 * 8;
    const short* fp1 = fp0 + 16 * D_;
    U4 a[8];
    {
      int bud = 0;
      while (true) {
        load_frag_sc0(fp0, a);
        load_frag_sc0(fp1, a + 4);
        unsigned bad = 0u;
#pragma unroll
        for (int i = 0; i < 8; ++i)
#pragma unroll
          for (int j = 0; j < 4; ++j) {
            unsigned d = a[i].u[j];
            bad |= ((d & 0xFFFFu) == SENT) | ((d >> 16) == SENT);
          }
        if (!__any((int)bad)) break;
        if (++bud >= 256) {                // staleness escape: drop clean stale lines
          bud = 0;
          __builtin_amdgcn_fence(__ATOMIC_ACQUIRE, "agent");
        }
      }
    }
    bf16x8 af[2][4];
#pragma unroll
    for (int mi = 0; mi < 2; ++mi)
#pragma unroll
      for (int kk = 0; kk < 4; ++kk)
        af[mi][kk] = a[mi * 4 + kk].v;

    // (B) MFMA partials
#pragma unroll
    for (int mi = 0; mi < 2; ++mi)
#pragma unroll
      for (int ni = 0; ni < 4; ++ni) {
        f32x4 acc = {0.f, 0.f, 0.f, 0.f};
#pragma unroll
        for (int kk = 0; kk < 4; ++kk)
          acc = __builtin_amdgcn_mfma_f32_16x16x32_bf16(af[mi][kk], bfrag[ni][kk], acc, 0, 0, 0);
        part[w][mi][ni][lane] = acc;
      }
    __syncthreads();                       // sync1: partials complete

    // (C) reduce across K-slices; tanh; publish slot t+1 (sc0 only -> local L2)
    f32x4 s = part[0][mi_e][ni_e][lane];
#pragma unroll
    for (int r = 1; r < 8; ++r) s += part[r][mi_e][ni_e][lane];

    const size_t nslot = (size_t)(t + 1) * (B_ * D_);
#pragma unroll
    for (int q2 = 0; q2 < 4; ++q2) {
      float v = fast_tanh(xv[q2] + s[q2] + hf[q2] * wd);
      hf[q2] = v;
      unsigned ov = (unsigned)(unsigned short)f2bf(v);
      short* pf = Af + nslot + (size_t)(mbase + q2) * D_ + n_e;
      asm volatile("global_store_short %0, %1, off sc0" :: "v"(pf), "v"(ov) : "memory");
    }

    // (D) prefetch next step's X gather (plain cached loads)
    if (t < T_ - 1) {
      int4 tk = *reinterpret_cast<const int4*>(idxT + (t + 1) * B_ + mbase);
      xv[0] = bf2f(*(const unsigned short*)(Wtb + (size_t)tk.x * D_ + n_e));
      xv[1] = bf2f(*(const unsigned short*)(Wtb + (size_t)tk.y * D_ + n_e));
      xv[2] = bf2f(*(const unsigned short*)(Wtb + (size_t)tk.z * D_ + n_e));
      xv[3] = bf2f(*(const unsigned short*)(Wtb + (size_t)tk.w * D_ + n_e));
    }

    asm volatile("s_waitcnt vmcnt(0)" ::: "memory");  // sc0 stores in L2
    __syncthreads();                       // sync2: part[] reusable; data published
  }
}

// ---------- logits GEMM: bf16 C into first 16KB of each row's 32KB out-slot ----------
// Cb[row][col] (bf16, row stride 16384 shorts) = sum_d A[row,d]*Wb[col,d] + b_o[col]
__global__ __launch_bounds__(256) void gemm_logits(const short* __restrict__ A,
                                                   const short* __restrict__ Bt,
                                                   const float* __restrict__ b_o,
                                                   short* __restrict__ Cb) {
  constexpr int K = D_;
  __shared__ __align__(16) short As[128 * 64];
  __shared__ __align__(16) short Bs[128 * 64];

  const int tid = threadIdx.x;
  const int lane = tid & 63;
  const int w = tid >> 6;
  const int wr = w >> 1, wc = w & 1;
  const int r0 = blockIdx.y * 128;
  const int c0 = blockIdx.x * 128;

  f32x4 acc[4][4] = {};

  for (int k0 = 0; k0 < K; k0 += 64) {
#pragma unroll
    for (int i = 0; i < 4; ++i) {
      int c = tid + 256 * i;
      int cb = (tid & ~63) + 256 * i;
      int row = c >> 3;
      int colc = ((c & 7) ^ (row & 7)) * 8;
      lds_load16(A + (size_t)(r0 + row) * K + k0 + colc, &As[cb * 8]);
      lds_load16(Bt + (size_t)(c0 + row) * K + k0 + colc, &Bs[cb * 8]);
    }
    asm volatile("s_waitcnt vmcnt(0)" ::: "memory");
    __syncthreads();

#pragma unroll
    for (int kk = 0; kk < 2; ++kk) {
      bf16x8 af[4], bfr[4];
      const int fcol = lane & 15;
      const int chunk = (kk * 4 + (lane >> 4)) ^ (fcol & 7);
#pragma unroll
      for (int i = 0; i < 4; ++i)
        af[i] = *reinterpret_cast<const bf16x8*>(&As[(wr * 64 + i * 16 + fcol) * 64 + chunk * 8]);
#pragma unroll
      for (int j = 0; j < 4; ++j)
        bfr[j] = *reinterpret_cast<const bf16x8*>(&Bs[(wc * 64 + j * 16 + fcol) * 64 + chunk * 8]);
#pragma unroll
      for (int i = 0; i < 4; ++i)
#pragma unroll
        for (int j = 0; j < 4; ++j)
          acc[i][j] = __builtin_amdgcn_mfma_f32_16x16x32_bf16(af[i], bfr[j], acc[i][j], 0, 0, 0);
    }
    __syncthreads();
  }

  const int fcol = lane & 15;
  const int frow = (lane >> 4) * 4;
#pragma unroll
  for (int i = 0; i < 4; ++i) {
    int row = r0 + wr * 64 + i * 16 + frow;
#pragma unroll
    for (int j = 0; j < 4; ++j) {
      int col = c0 + wc * 64 + j * 16 + fcol;
      float bias = b_o[col];
#pragma unroll
      for (int q = 0; q < 4; ++q)
        Cb[(size_t)(row + q) * 16384 + col] = f2bf(acc[i][j][q] + bias);
    }
  }
}

// ---------- log-softmax: read bf16 row (first 16KB of slot), write f32 in place ----------
__global__ __launch_bounds__(256) void logsoftmax(float* __restrict__ out) {
  __shared__ float red[4];
  __shared__ float red2[4];
  const short* row = (const short*)out + (size_t)blockIdx.x * 16384;
  float* orow = out + (size_t)blockIdx.x * V_;
  const int tid = threadIdx.x;

  float v[32];
  float mx = -1e30f;
#pragma unroll
  for (int i = 0; i < 4; ++i) {
    uint4 pk = reinterpret_cast<const uint4*>(row)[i * 256 + tid];
    unsigned uu[4] = {pk.x, pk.y, pk.z, pk.w};
#pragma unroll
    for (int j = 0; j < 4; ++j) {
      float lo = bf2f((unsigned short)(uu[j] & 0xFFFFu));
      float hi = bf2f((unsigned short)(uu[j] >> 16));
      v[i * 8 + 2 * j] = lo;
      v[i * 8 + 2 * j + 1] = hi;
      mx = fmaxf(mx, fmaxf(lo, hi));
    }
  }
#pragma unroll
  for (int off = 32; off > 0; off >>= 1) mx = fmaxf(mx, __shfl_xor(mx, off, 64));
  if ((tid & 63) == 0) red[tid >> 6] = mx;
  __syncthreads();   // also orders: all bf16 reads complete before any f32 write
  mx = fmaxf(fmaxf(red[0], red[1]), fmaxf(red[2], red[3]));

  float sum = 0.f;
#pragma unroll
  for (int k = 0; k < 32; ++k) sum += expf(v[k] - mx);
#pragma unroll
  for (int off = 32; off > 0; off >>= 1) sum += __shfl_xor(sum, off, 64);
  if ((tid & 63) == 0) red2[tid >> 6] = sum;
  __syncthreads();
  sum = (red2[0] + red2[1]) + (red2[2] + red2[3]);

  const float lse = mx + logf(sum);
#pragma unroll
  for (int i = 0; i < 4; ++i) {
    float4 w1 = {v[i * 8 + 0] - lse, v[i * 8 + 1] - lse, v[i * 8 + 2] - lse, v[i * 8 + 3] - lse};
    float4 w2 = {v[i * 8 + 4] - lse, v[i * 8 + 5] - lse, v[i * 8 + 6] - lse, v[i * 8 + 7] - lse};
    *reinterpret_cast<float4*>(&orow[(i * 256 + tid) * 8]) = w1;
    *reinterpret_cast<float4*>(&orow[(i * 256 + tid) * 8 + 4]) = w2;
  }
}

extern "C" void kernel_launch(void* const* d_in, const int* in_sizes, int n_in,
                              void* d_out, int out_size, void* d_ws, size_t ws_size,
                              hipStream_t stream) {
  const int* idx = (const int*)d_in[0];
  const float* h0 = (const float*)d_in[1];
  const float* W_ih = (const float*)d_in[2];
  const float* b_ih = (const float*)d_in[3];
  const float* W_hh = (const float*)d_in[4];
  const float* b_hh = (const float*)d_in[5];
  const float* W_ho = (const float*)d_in[6];
  const float* b_o = (const float*)d_in[7];
  float* out = (float*)d_out;

  // workspace layout (~52.6 MB):
  // (unused)                  8454144 B @ 0
  // Wb  bf16 [8192][1024]    16777216 B @ 8454144
  // Rb  bf16 [1024][1024]     2097152 B @ 25231360
  // Wdiag f32 [1024]             4096 B @ 27328512
  // Wtb bf16 [8192][1024]    16777216 B @ 27332608
  // flags u32 [64] (cnt 16..23 / winner 24 / ready 25) @ 44109824
  // idxT int [128][32]          16384 B @ 44113920
  // Af  bf16 [129][32][1024]  8454144 B @ 44130304   (sc0/winner-L2 exchange)
  char* ws = (char*)d_ws;
  short* Wb = (short*)(ws + 8454144);
  short* Rb = (short*)(ws + 25231360);
  float* Wdiag = (float*)(ws + 27328512);
  short* Wtb = (short*)(ws + 27332608);
  unsigned* flags = (unsigned*)(ws + 44109824);
  int* idxT = (int*)(ws + 44113920);
  short* Af = (short*)(ws + 44130304);

  conv_bf16_k<<<dim3(8192), dim3(256), 0, stream>>>(W_ho, Wb, (V_ * D_) / 4);
  conv_whh<<<dim3(4096), dim3(256), 0, stream>>>(W_hh, Rb, Wdiag);
  poison_h<<<dim3(4096), dim3(256), 0, stream>>>(
      (unsigned long long*)(Af + B_ * D_), (T_ * B_ * D_) / 4);
  init_h<<<dim3(64), dim3(256), 0, stream>>>(h0, idx, Af, flags, idxT);
  wtrans<<<dim3(V_ / 32, D_ / 32), dim3(256), 0, stream>>>(W_ih, b_ih, b_hh, Wtb);

  rnn_all<<<dim3(256), dim3(512), 0, stream>>>(Rb, Wdiag, h0, Wtb, idxT, Af, flags);

  // logits for step t read Af slot t+1  ->  A = Af + 32768; bf16 C into d_out slots
  gemm_logits<<<dim3(V_ / 128, (T_ * B_) / 128), dim3(256), 0, stream>>>(
      Af + B_ * D_, Wb, b_o, (short*)out);
  logsoftmax<<<dim3(T_ * B_), dim3(256), 0, stream>>>(out);
}